// Round 4
// baseline (220.586 us; speedup 1.0000x reference)
//
#include <hip/hip_runtime.h>

#define ROWS 4
#define N 4096
#define BATCH 8192
#define PAD_STRIDE 264              // 256 + 8 words: breaks power-of-2 bank stride
#define BUF_WORDS (16 * PAD_STRIDE) // 4224 floats = 16896 B single transpose buffer

typedef float v4f __attribute__((ext_vector_type(4)));

__device__ __forceinline__ void layer_compute(float (&v)[ROWS][16],
                                              const float4 (&w)[8],
                                              const int bit) {
    const int d = 1 << bit;
    #pragma unroll
    for (int r = 0; r < ROWS; ++r) {
        #pragma unroll
        for (int pc = 0; pc < 8; ++pc) {
            const int lo = ((pc >> bit) << (bit + 1)) | (pc & (d - 1));
            const int hi = lo + d;
            const float top = v[r][lo];
            const float bot = v[r][hi];
            v[r][lo] = w[pc].x * top + w[pc].y * bot;
            v[r][hi] = w[pc].z * top + w[pc].w * bot;
        }
    }
}

// Single-buffer LDS transpose (16.9 KB): write/sync/read/sync per row.
// Rationale (R3 counters): double-buffer (33.8 KB) left only ~9 waves/CU
// resident (Occupancy 29%) — LDS-capped. Halving LDS lifts the block cap;
// VGPR (<=102 via launch_bounds 5) becomes the limiter at ~5-6 waves/SIMD.
__global__ __launch_bounds__(256, 5)
void butterfly_kernel(const float* __restrict__ x,
                      const float* __restrict__ tw,
                      float* __restrict__ out) {
    __shared__ float lds[BUF_WORDS];
    const int t   = threadIdx.x;
    const int thi = t >> 4;   // t / 16
    const int tlo = t & 15;   // t % 16
    const int row0 = blockIdx.x * ROWS;

    const float4* tw4 = (const float4*)tw;

    float v[ROWS][16];

    // ---- Load: v[r][a] = x[(row0+r)*N + a*256 + t]  (coalesced dword per a)
    #pragma unroll
    for (int r = 0; r < ROWS; ++r) {
        const float* xr = x + (size_t)(row0 + r) * N + t;
        #pragma unroll
        for (int a = 0; a < 16; ++a)
            v[r][a] = __builtin_nontemporal_load(xr + a * 256);
    }

    // ---- Stage A: layers 0..3 (strides 2048,1024,512,256) — pair dim = a
    #pragma unroll
    for (int l = 0; l < 4; ++l) {
        float4 w[8];
        #pragma unroll
        for (int pc = 0; pc < 8; ++pc)
            w[pc] = tw4[l * 2048 + pc * 256 + t];   // p = pc*256 + t
        layer_compute(v, w, 3 - l);
    }

    // ---- Transpose A->B: thread t held (b=thi,c=tlo) all-a; becomes (a=thi,c=tlo) all-b
    #pragma unroll
    for (int r = 0; r < ROWS; ++r) {
        #pragma unroll
        for (int a = 0; a < 16; ++a)
            lds[a * PAD_STRIDE + t] = v[r][a];      // stride-1 across lanes: conflict-free
        __syncthreads();
        #pragma unroll
        for (int b = 0; b < 16; ++b)                // 2-way conflict (free)
            v[r][b] = lds[thi * PAD_STRIDE + b * 16 + tlo];
        __syncthreads();
    }

    // ---- Stage B: layers 4..7 (strides 128,64,32,16) — pair dim = b
    #pragma unroll
    for (int l = 4; l < 8; ++l) {
        float4 w[8];
        #pragma unroll
        for (int pc = 0; pc < 8; ++pc)
            w[pc] = tw4[l * 2048 + thi * 128 + pc * 16 + tlo]; // p = a*128+pc*16+c
        layer_compute(v, w, 3 - (l - 4));
    }

    // ---- Transpose B->C: thread becomes (a=thi,b=tlo) holding contiguous c
    #pragma unroll
    for (int r = 0; r < ROWS; ++r) {
        #pragma unroll
        for (int b = 0; b < 16; ++b)                // 2-way conflict (free)
            lds[thi * PAD_STRIDE + b * 16 + tlo] = v[r][b];
        __syncthreads();
        const float* bp = &lds[thi * PAD_STRIDE + tlo * 16];
        #pragma unroll
        for (int q = 0; q < 4; ++q) {               // contiguous b128 reads
            v4f c4 = *(const v4f*)(bp + 4 * q);
            v[r][4 * q + 0] = c4.x;
            v[r][4 * q + 1] = c4.y;
            v[r][4 * q + 2] = c4.z;
            v[r][4 * q + 3] = c4.w;
        }
        if (r != ROWS - 1) __syncthreads();
    }

    // ---- Stage C: layers 8..11 (strides 8,4,2,1) — pair dim = c
    #pragma unroll
    for (int l = 8; l < 12; ++l) {
        float4 w[8];
        #pragma unroll
        for (int pc = 0; pc < 8; ++pc)
            w[pc] = tw4[l * 2048 + thi * 128 + tlo * 8 + pc];  // p = a*128+b*8+pc
        layer_compute(v, w, 3 - (l - 8));
    }

    // ---- Store: thread holds elements [16t, 16t+16) of each row — 4x float4.
    // Plain write-back stores: L2 merges the 64B-strided 16B chunks into full
    // lines (nt hint here caused 2.6x write amplification — R2 counters).
    #pragma unroll
    for (int r = 0; r < ROWS; ++r) {
        float* orow = out + (size_t)(row0 + r) * N + 16 * t;
        #pragma unroll
        for (int q = 0; q < 4; ++q) {
            v4f s4;
            s4.x = v[r][4 * q + 0];
            s4.y = v[r][4 * q + 1];
            s4.z = v[r][4 * q + 2];
            s4.w = v[r][4 * q + 3];
            *(v4f*)(orow + 4 * q) = s4;
        }
    }
}

extern "C" void kernel_launch(void* const* d_in, const int* in_sizes, int n_in,
                              void* d_out, int out_size, void* d_ws, size_t ws_size,
                              hipStream_t stream) {
    const float* x  = (const float*)d_in[0];
    const float* tw = (const float*)d_in[1];
    float* out      = (float*)d_out;
    dim3 grid(BATCH / ROWS);
    dim3 block(256);
    hipLaunchKernelGGL(butterfly_kernel, grid, block, 0, stream, x, tw, out);
}

// Round 5
// 175.458 us; speedup vs baseline: 1.2572x; 1.2572x over previous
//
#include <hip/hip_runtime.h>

#define ROWS 4
#define N 4096
#define BATCH 8192
#define PAD_STRIDE 264              // 256 + 8 words: breaks power-of-2 bank stride
#define BUF_WORDS (16 * PAD_STRIDE) // 4224 floats = 16896 B single transpose buffer

typedef float v4f __attribute__((ext_vector_type(4)));

__device__ __forceinline__ void layer_compute(float (&v)[ROWS][16],
                                              const float4 (&w)[8],
                                              const int bit) {
    const int d = 1 << bit;
    #pragma unroll
    for (int r = 0; r < ROWS; ++r) {
        #pragma unroll
        for (int pc = 0; pc < 8; ++pc) {
            const int lo = ((pc >> bit) << (bit + 1)) | (pc & (d - 1));
            const int hi = lo + d;
            const float top = v[r][lo];
            const float bot = v[r][hi];
            v[r][lo] = w[pc].x * top + w[pc].y * bot;
            v[r][hi] = w[pc].z * top + w[pc].w * bot;
        }
    }
}

// Single-buffer LDS transpose (16.9 KB) lifts the LDS block cap (R3: 33.8KB
// double-buffer -> ~29% occupancy). launch_bounds min-waves=4 (VGPR cap 128):
// R4's min-waves=5 clamped VGPR to 48 < the 64-float live state -> scratch
// spills (FETCH 234MB / WRITE 466MB). 4 leaves the natural 84-VGPR allocation
// intact (6 waves/SIMD by VGPR).
__global__ __launch_bounds__(256, 4)
void butterfly_kernel(const float* __restrict__ x,
                      const float* __restrict__ tw,
                      float* __restrict__ out) {
    __shared__ float lds[BUF_WORDS];
    const int t   = threadIdx.x;
    const int thi = t >> 4;   // t / 16
    const int tlo = t & 15;   // t % 16
    const int row0 = blockIdx.x * ROWS;

    const float4* tw4 = (const float4*)tw;

    float v[ROWS][16];

    // ---- Load: v[r][a] = x[(row0+r)*N + a*256 + t]  (coalesced dword per a)
    #pragma unroll
    for (int r = 0; r < ROWS; ++r) {
        const float* xr = x + (size_t)(row0 + r) * N + t;
        #pragma unroll
        for (int a = 0; a < 16; ++a)
            v[r][a] = __builtin_nontemporal_load(xr + a * 256);
    }

    // ---- Stage A: layers 0..3 (strides 2048,1024,512,256) — pair dim = a
    #pragma unroll
    for (int l = 0; l < 4; ++l) {
        float4 w[8];
        #pragma unroll
        for (int pc = 0; pc < 8; ++pc)
            w[pc] = tw4[l * 2048 + pc * 256 + t];   // p = pc*256 + t
        layer_compute(v, w, 3 - l);
    }

    // ---- Transpose A->B: thread t held (b=thi,c=tlo) all-a; becomes (a=thi,c=tlo) all-b
    #pragma unroll
    for (int r = 0; r < ROWS; ++r) {
        #pragma unroll
        for (int a = 0; a < 16; ++a)
            lds[a * PAD_STRIDE + t] = v[r][a];      // stride-1 across lanes: conflict-free
        __syncthreads();
        #pragma unroll
        for (int b = 0; b < 16; ++b)                // 2-way conflict (free)
            v[r][b] = lds[thi * PAD_STRIDE + b * 16 + tlo];
        __syncthreads();
    }

    // ---- Stage B: layers 4..7 (strides 128,64,32,16) — pair dim = b
    #pragma unroll
    for (int l = 4; l < 8; ++l) {
        float4 w[8];
        #pragma unroll
        for (int pc = 0; pc < 8; ++pc)
            w[pc] = tw4[l * 2048 + thi * 128 + pc * 16 + tlo]; // p = a*128+pc*16+c
        layer_compute(v, w, 3 - (l - 4));
    }

    // ---- Transpose B->C: thread becomes (a=thi,b=tlo) holding contiguous c
    #pragma unroll
    for (int r = 0; r < ROWS; ++r) {
        #pragma unroll
        for (int b = 0; b < 16; ++b)                // 2-way conflict (free)
            lds[thi * PAD_STRIDE + b * 16 + tlo] = v[r][b];
        __syncthreads();
        const float* bp = &lds[thi * PAD_STRIDE + tlo * 16];
        #pragma unroll
        for (int q = 0; q < 4; ++q) {               // contiguous b128 reads
            v4f c4 = *(const v4f*)(bp + 4 * q);
            v[r][4 * q + 0] = c4.x;
            v[r][4 * q + 1] = c4.y;
            v[r][4 * q + 2] = c4.z;
            v[r][4 * q + 3] = c4.w;
        }
        if (r != ROWS - 1) __syncthreads();
    }

    // ---- Stage C: layers 8..11 (strides 8,4,2,1) — pair dim = c
    #pragma unroll
    for (int l = 8; l < 12; ++l) {
        float4 w[8];
        #pragma unroll
        for (int pc = 0; pc < 8; ++pc)
            w[pc] = tw4[l * 2048 + thi * 128 + tlo * 8 + pc];  // p = a*128+b*8+pc
        layer_compute(v, w, 3 - (l - 8));
    }

    // ---- Store: thread holds elements [16t, 16t+16) of each row — 4x float4.
    // Plain write-back stores: L2 merges the 64B-strided 16B chunks into full
    // lines (nt hint here caused 2.6x write amplification — R2 counters).
    #pragma unroll
    for (int r = 0; r < ROWS; ++r) {
        float* orow = out + (size_t)(row0 + r) * N + 16 * t;
        #pragma unroll
        for (int q = 0; q < 4; ++q) {
            v4f s4;
            s4.x = v[r][4 * q + 0];
            s4.y = v[r][4 * q + 1];
            s4.z = v[r][4 * q + 2];
            s4.w = v[r][4 * q + 3];
            *(v4f*)(orow + 4 * q) = s4;
        }
    }
}

extern "C" void kernel_launch(void* const* d_in, const int* in_sizes, int n_in,
                              void* d_out, int out_size, void* d_ws, size_t ws_size,
                              hipStream_t stream) {
    const float* x  = (const float*)d_in[0];
    const float* tw = (const float*)d_in[1];
    float* out      = (float*)d_out;
    dim3 grid(BATCH / ROWS);
    dim3 block(256);
    hipLaunchKernelGGL(butterfly_kernel, grid, block, 0, stream, x, tw, out);
}

// Round 6
// 113.155 us; speedup vs baseline: 1.9494x; 1.5506x over previous
//
#include <hip/hip_runtime.h>

#define ROWS 4
#define N 4096
#define BATCH 8192
#define PAD_STRIDE 264              // 256 + 8 words: breaks power-of-2 bank stride
#define BUF_WORDS (16 * PAD_STRIDE) // 4224 floats = 16896 B single transpose buffer

typedef float v4f __attribute__((ext_vector_type(4)));

__device__ __forceinline__ void layer_compute(float (&v)[ROWS][16],
                                              const float4 (&w)[8],
                                              const int bit) {
    const int d = 1 << bit;
    #pragma unroll
    for (int r = 0; r < ROWS; ++r) {
        #pragma unroll
        for (int pc = 0; pc < 8; ++pc) {
            const int lo = ((pc >> bit) << (bit + 1)) | (pc & (d - 1));
            const int hi = lo + d;
            const float top = v[r][lo];
            const float bot = v[r][hi];
            v[r][lo] = w[pc].x * top + w[pc].y * bot;
            v[r][hi] = w[pc].z * top + w[pc].w * bot;
        }
    }
}

// launch_bounds(256,3): empirically (R3/R4/R5) this toolchain's VGPR cap is
// ~256/min_waves: arg3->84 (no spill), arg4->64 (spill), arg5->48 (heavy
// spill). 84 VGPR is the natural spill-free allocation for the 64-float live
// state. Single 16.9KB LDS buffer (vs R3's 33.8KB double) lifts the LDS
// block cap ~3->8 blocks/CU; limiter becomes the VGPR HW quantum (4 w/SIMD).
__global__ __launch_bounds__(256, 3)
void butterfly_kernel(const float* __restrict__ x,
                      const float* __restrict__ tw,
                      float* __restrict__ out) {
    __shared__ float lds[BUF_WORDS];
    const int t   = threadIdx.x;
    const int thi = t >> 4;   // t / 16
    const int tlo = t & 15;   // t % 16
    const int row0 = blockIdx.x * ROWS;

    const float4* tw4 = (const float4*)tw;

    float v[ROWS][16];

    // ---- Load: v[r][a] = x[(row0+r)*N + a*256 + t]  (coalesced dword per a)
    #pragma unroll
    for (int r = 0; r < ROWS; ++r) {
        const float* xr = x + (size_t)(row0 + r) * N + t;
        #pragma unroll
        for (int a = 0; a < 16; ++a)
            v[r][a] = __builtin_nontemporal_load(xr + a * 256);
    }

    // ---- Stage A: layers 0..3 (strides 2048,1024,512,256) — pair dim = a
    #pragma unroll
    for (int l = 0; l < 4; ++l) {
        float4 w[8];
        #pragma unroll
        for (int pc = 0; pc < 8; ++pc)
            w[pc] = tw4[l * 2048 + pc * 256 + t];   // p = pc*256 + t
        layer_compute(v, w, 3 - l);
    }

    // ---- Transpose A->B: thread t held (b=thi,c=tlo) all-a; becomes (a=thi,c=tlo) all-b
    #pragma unroll
    for (int r = 0; r < ROWS; ++r) {
        #pragma unroll
        for (int a = 0; a < 16; ++a)
            lds[a * PAD_STRIDE + t] = v[r][a];      // stride-1 across lanes: conflict-free
        __syncthreads();
        #pragma unroll
        for (int b = 0; b < 16; ++b)                // 2-way conflict (free)
            v[r][b] = lds[thi * PAD_STRIDE + b * 16 + tlo];
        __syncthreads();
    }

    // ---- Stage B: layers 4..7 (strides 128,64,32,16) — pair dim = b
    #pragma unroll
    for (int l = 4; l < 8; ++l) {
        float4 w[8];
        #pragma unroll
        for (int pc = 0; pc < 8; ++pc)
            w[pc] = tw4[l * 2048 + thi * 128 + pc * 16 + tlo]; // p = a*128+pc*16+c
        layer_compute(v, w, 3 - (l - 4));
    }

    // ---- Transpose B->C: thread becomes (a=thi,b=tlo) holding contiguous c
    #pragma unroll
    for (int r = 0; r < ROWS; ++r) {
        #pragma unroll
        for (int b = 0; b < 16; ++b)                // 2-way conflict (free)
            lds[thi * PAD_STRIDE + b * 16 + tlo] = v[r][b];
        __syncthreads();
        const float* bp = &lds[thi * PAD_STRIDE + tlo * 16];
        #pragma unroll
        for (int q = 0; q < 4; ++q) {               // contiguous b128 reads
            v4f c4 = *(const v4f*)(bp + 4 * q);
            v[r][4 * q + 0] = c4.x;
            v[r][4 * q + 1] = c4.y;
            v[r][4 * q + 2] = c4.z;
            v[r][4 * q + 3] = c4.w;
        }
        if (r != ROWS - 1) __syncthreads();
    }

    // ---- Stage C: layers 8..11 (strides 8,4,2,1) — pair dim = c
    #pragma unroll
    for (int l = 8; l < 12; ++l) {
        float4 w[8];
        #pragma unroll
        for (int pc = 0; pc < 8; ++pc)
            w[pc] = tw4[l * 2048 + thi * 128 + tlo * 8 + pc];  // p = a*128+b*8+pc
        layer_compute(v, w, 3 - (l - 8));
    }

    // ---- Store: thread holds elements [16t, 16t+16) of each row — 4x float4.
    // Plain write-back stores: L2 merges the 64B-strided 16B chunks into full
    // lines (nt hint here caused 2.6x write amplification — R2 counters).
    #pragma unroll
    for (int r = 0; r < ROWS; ++r) {
        float* orow = out + (size_t)(row0 + r) * N + 16 * t;
        #pragma unroll
        for (int q = 0; q < 4; ++q) {
            v4f s4;
            s4.x = v[r][4 * q + 0];
            s4.y = v[r][4 * q + 1];
            s4.z = v[r][4 * q + 2];
            s4.w = v[r][4 * q + 3];
            *(v4f*)(orow + 4 * q) = s4;
        }
    }
}

extern "C" void kernel_launch(void* const* d_in, const int* in_sizes, int n_in,
                              void* d_out, int out_size, void* d_ws, size_t ws_size,
                              hipStream_t stream) {
    const float* x  = (const float*)d_in[0];
    const float* tw = (const float*)d_in[1];
    float* out      = (float*)d_out;
    dim3 grid(BATCH / ROWS);
    dim3 block(256);
    hipLaunchKernelGGL(butterfly_kernel, grid, block, 0, stream, x, tw, out);
}